// Round 1
// baseline (21764.534 us; speedup 1.0000x reference)
//
#include <hip/hip_runtime.h>
#include <math.h>

// ---------------- problem constants ----------------
#define TN   256     // memory slots
#define TWM  64      // word size
#define TR   4       // read heads
#define TH   512     // hidden
#define TD   512     // input dim
#define TT   128     // time steps
#define TB   32      // batch
#define IFACE 471
#define EPSI 1e-6f

// ---------------- workspace layout (floats) ----------------
#define OFF_H      0          // 2 x 32*512 (double buffered by t parity)
#define OFF_C      32768      // 32*512
#define OFF_M      49152      // 32*256*64
#define OFF_USAGE  573440     // 32*256
#define OFF_RW     581632     // 32*4*256
#define OFF_WW     614400     // 32*256
#define OFF_PREC   622592     // 32*256
#define OFF_LINK   630784     // 32*256*256
#define OFF_RVEC   2727936    // 32*256
#define TOTAL_STATE 2736128

__device__ __forceinline__ float sigm(float x)  { return 1.0f / (1.0f + expf(-x)); }
__device__ __forceinline__ float softpl(float x){ return x > 20.0f ? x : log1pf(expf(x)); }

// ---------------- init: zero state, M = EPS ----------------
__global__ void k_init(float* ws) {
    int idx = blockIdx.x * 256 + threadIdx.x;
    if (idx < TOTAL_STATE)
        ws[idx] = (idx >= OFF_M && idx < OFF_M + TB*TN*TWM) ? EPSI : 0.0f;
}

// ---------------- kernel A: gates GEMM + LSTM pointwise ----------------
// grid 128 blocks (4 hidden units each, 16 gate-cols), 256 threads.
// gates = [x_t, rvec, h] @ [Wx; Wh] + b  (virtual K = 1280)
__global__ __launch_bounds__(256) void k_gates(
    const float* __restrict__ emb, const float* __restrict__ Wx,
    const float* __restrict__ Wh,  const float* __restrict__ b_lstm,
    float* __restrict__ ws, int t)
{
    __shared__ __align__(16) float smem[8192];
    const int tid = threadIdx.x;
    const int u0  = blockIdx.x * 4;
    const int cg  = tid & 3;          // gate index (column group of 4 units)
    const int bg  = (tid >> 2) & 7;   // batch group (4 batches)
    const int ks  = tid >> 5;         // k-split 0..7
    const int col0 = cg * 512 + u0;
    const float* hbuf = ws + OFF_H + (t & 1) * (TB * TH);

    float acc[4][4] = {};

    for (int tile = 0; tile < 5; ++tile) {
        const int T0 = tile * 256;
        // ---- cooperative act-tile load: smem[k_local][b], 256 k x 32 b ----
        {
            const int b = tid & 31, kf8 = tid >> 5;
            #pragma unroll
            for (int i = 0; i < 8; ++i) {
                const int kf = kf8 * 8 + i;     // 0..63 float4 chunks
                const int kl = kf * 4;
                const int k  = T0 + kl;
                const float* src;
                if (k < 512)      src = emb + (size_t)t * (TB*TD) + b * TD + k;
                else if (k < 768) src = ws + OFF_RVEC + b * 256 + (k - 512);
                else              src = hbuf + b * TH + (k - 768);
                float4 v = *(const float4*)src;
                smem[(kl+0)*32 + b] = v.x;
                smem[(kl+1)*32 + b] = v.y;
                smem[(kl+2)*32 + b] = v.z;
                smem[(kl+3)*32 + b] = v.w;
            }
        }
        __syncthreads();
        // ---- compute this tile's 32 k's for this thread ----
        {
            const int k0 = T0 + ks * 32;
            const float* wp = (k0 < 768 ? Wx + (size_t)k0 * 2048
                                        : Wh + (size_t)(k0 - 768) * 2048) + col0;
            const float* ap = &smem[(ks * 32) * 32 + bg * 4];
            #pragma unroll 8
            for (int kk = 0; kk < 32; ++kk) {
                float4 wv = *(const float4*)wp; wp += 2048;
                float4 av = *(const float4*)ap; ap += 32;
                acc[0][0] += wv.x*av.x; acc[0][1] += wv.x*av.y; acc[0][2] += wv.x*av.z; acc[0][3] += wv.x*av.w;
                acc[1][0] += wv.y*av.x; acc[1][1] += wv.y*av.y; acc[1][2] += wv.y*av.z; acc[1][3] += wv.y*av.w;
                acc[2][0] += wv.z*av.x; acc[2][1] += wv.z*av.y; acc[2][2] += wv.z*av.z; acc[2][3] += wv.z*av.w;
                acc[3][0] += wv.w*av.x; acc[3][1] += wv.w*av.y; acc[3][2] += wv.w*av.z; acc[3][3] += wv.w*av.w;
            }
        }
        __syncthreads();
    }

    // ---- write k-split partials to LDS [ks][512] ----
    {
        const int rbase = ks * 512 + (cg * 8 + bg) * 16;
        *(float4*)&smem[rbase + 0]  = make_float4(acc[0][0], acc[0][1], acc[0][2], acc[0][3]);
        *(float4*)&smem[rbase + 4]  = make_float4(acc[1][0], acc[1][1], acc[1][2], acc[1][3]);
        *(float4*)&smem[rbase + 8]  = make_float4(acc[2][0], acc[2][1], acc[2][2], acc[2][3]);
        *(float4*)&smem[rbase + 12] = make_float4(acc[3][0], acc[3][1], acc[3][2], acc[3][3]);
    }
    __syncthreads();
    // ---- reduce 8 partials, add bias, store gates to smem[4096+..] ----
    #pragma unroll
    for (int rep = 0; rep < 2; ++rep) {
        const int o = tid + rep * 256;
        float s = 0.0f;
        #pragma unroll
        for (int kq = 0; kq < 8; ++kq) s += smem[kq * 512 + o];
        const int ocg = o >> 7, obg = (o >> 4) & 7, odu = (o >> 2) & 3, obb = o & 3;
        s += b_lstm[ocg * 512 + u0 + odu];
        smem[4096 + (ocg * 4 + odu) * 32 + (obg * 4 + obb)] = s;
    }
    __syncthreads();
    // ---- LSTM pointwise for 4 units x 32 batches ----
    if (tid < 128) {
        const int du = tid >> 5, b = tid & 31;
        const float ig = smem[4096 + (0  + du) * 32 + b];
        const float fg = smem[4096 + (4  + du) * 32 + b];
        const float gg = smem[4096 + (8  + du) * 32 + b];
        const float og = smem[4096 + (12 + du) * 32 + b];
        const int ci = b * TH + u0 + du;
        const float cold = ws[OFF_C + ci];
        const float cn = sigm(fg) * cold + sigm(ig) * tanhf(gg);
        const float hn = sigm(og) * tanhf(cn);
        ws[OFF_C + ci] = cn;
        ws[OFF_H + ((t + 1) & 1) * (TB * TH) + ci] = hn;
    }
}

// ---------------- kernel B: per-batch DNC memory step ----------------
// grid 32 blocks (one per batch), 1024 threads.
__global__ __launch_bounds__(1024) void k_step(
    const float* __restrict__ W_if,  const float* __restrict__ b_if,
    const float* __restrict__ W_pre, const float* __restrict__ b_pre,
    const float* __restrict__ W_rout,
    float* __restrict__ ws, float* __restrict__ out, int t)
{
    __shared__ __align__(16) float h_s[512];
    __shared__ __align__(16) float hpre_s[512];
    __shared__ __align__(16) float z_s[472];
    __shared__ __align__(16) float rw_s[4][256];
    __shared__ __align__(16) float ww_old_s[256];
    __shared__ __align__(16) float ww_s[256];
    __shared__ __align__(16) float u_s[256];
    __shared__ __align__(16) float prec_s[256];
    __shared__ __align__(16) float prec_new_s[256];
    __shared__ __align__(16) float alloc_s[256];   // later reused as rvec
    __shared__ __align__(16) float cw_s[256];
    __shared__ __align__(16) float cr_s[4][256];
    __shared__ __align__(16) float fw_s[4][256];
    __shared__ __align__(16) float bw_s[4][256];
    __shared__ __align__(16) float keys_s[4][64];
    __shared__ __align__(16) float wkey_s[64];
    __shared__ __align__(16) float erase_s[64];
    __shared__ __align__(16) float wvec_s[64];
    __shared__ __align__(16) float mnorm_s[256];
    __shared__ __align__(16) float rstr_s[4];
    __shared__ __align__(16) float free_s[4];
    __shared__ __align__(16) float modes_s[4][3];
    __shared__ __align__(16) float knorm_s[8];
    __shared__ __align__(16) float sred_s[16];
    __shared__ __align__(16) float sc_s[8];        // 0 wstr, 1 ag, 2 wg, 3 sumww, 4 gmax, 5 gsum
    __shared__ __align__(16) float gmax_s[4];
    __shared__ __align__(16) float gsum_s[4];
    __shared__ __align__(16) float Lt_s[32 * 256]; // link chunk tile / generic scratch

    const int b   = blockIdx.x;
    const int tid = threadIdx.x;
    const float* wsH = ws + OFF_H + ((t + 1) & 1) * (TB * TH) + b * TH;
    float* wsM = ws + OFF_M + b * (TN * TWM);
    float* wsL = ws + OFF_LINK + (size_t)b * (TN * TN);

    // ---- phase 0: stage state into LDS ----
    if (tid < 128)       { *(float4*)&h_s[tid*4] = *(const float4*)&wsH[tid*4]; }
    else if (tid < 384)  { const int i = tid-128; *(float4*)&((float*)rw_s)[i*4] = *(const float4*)&ws[OFF_RW + b*1024 + i*4]; }
    else if (tid < 448)  { const int i = tid-384; *(float4*)&ww_old_s[i*4] = *(const float4*)&ws[OFF_WW + b*256 + i*4]; }
    else if (tid < 512)  { const int i = tid-448; *(float4*)&u_s[i*4]      = *(const float4*)&ws[OFF_USAGE + b*256 + i*4]; }
    else if (tid < 576)  { const int i = tid-512; *(float4*)&prec_s[i*4]   = *(const float4*)&ws[OFF_PREC + b*256 + i*4]; }
    __syncthreads();

    // ---- phase 1: z = h@W_iface + b_iface ; hpre = h@W_pre + b_pre ----
    {
        const int jg = tid >> 3, kq = tid & 7;
        const int j0 = jg * 4;
        // z (row stride 471, unaligned -> scalar col loads)
        float a0=0, a1=0, a2=0, a3=0;
        if (j0 < IFACE) {
            const int c1 = ((j0+1 < IFACE) ? j0+1 : IFACE-1) - j0;
            const int c2 = ((j0+2 < IFACE) ? j0+2 : IFACE-1) - j0;
            const int c3 = ((j0+3 < IFACE) ? j0+3 : IFACE-1) - j0;
            const float* wb = W_if + (size_t)(kq * 64) * IFACE + j0;
            #pragma unroll 4
            for (int kk = 0; kk < 64; ++kk) {
                const float hv = h_s[kq * 64 + kk];
                a0 += hv * wb[0]; a1 += hv * wb[c1]; a2 += hv * wb[c2]; a3 += hv * wb[c3];
                wb += IFACE;
            }
        }
        #pragma unroll
        for (int m = 1; m <= 4; m <<= 1) {
            a0 += __shfl_xor(a0, m); a1 += __shfl_xor(a1, m);
            a2 += __shfl_xor(a2, m); a3 += __shfl_xor(a3, m);
        }
        if (kq == 0 && j0 < IFACE) {
            z_s[j0] = a0 + b_if[j0];
            if (j0+1 < IFACE) z_s[j0+1] = a1 + b_if[j0+1];
            if (j0+2 < IFACE) z_s[j0+2] = a2 + b_if[j0+2];
            if (j0+3 < IFACE) z_s[j0+3] = a3 + b_if[j0+3];
        }
        // hpre (row stride 512, aligned float4)
        float p0=0, p1=0, p2=0, p3=0;
        {
            const float* wb = W_pre + (size_t)(kq * 64) * 512 + j0;
            #pragma unroll 4
            for (int kk = 0; kk < 64; ++kk) {
                const float hv = h_s[kq * 64 + kk];
                float4 w = *(const float4*)wb; wb += 512;
                p0 += hv * w.x; p1 += hv * w.y; p2 += hv * w.z; p3 += hv * w.w;
            }
        }
        #pragma unroll
        for (int m = 1; m <= 4; m <<= 1) {
            p0 += __shfl_xor(p0, m); p1 += __shfl_xor(p1, m);
            p2 += __shfl_xor(p2, m); p3 += __shfl_xor(p3, m);
        }
        if (kq == 0) {
            hpre_s[j0]   = p0 + b_pre[j0];
            hpre_s[j0+1] = p1 + b_pre[j0+1];
            hpre_s[j0+2] = p2 + b_pre[j0+2];
            hpre_s[j0+3] = p3 + b_pre[j0+3];
        }
    }
    __syncthreads();

    // ---- phase 2a: parse interface vector ----
    if (tid < IFACE) {
        const float v = z_s[tid];
        if (tid < 256)       keys_s[tid >> 6][tid & 63] = v;
        else if (tid < 260)  rstr_s[tid - 256] = 1.0f + softpl(v);
        else if (tid < 324)  wkey_s[tid - 260] = v;
        else if (tid == 324) sc_s[0] = 1.0f + softpl(v);
        else if (tid < 389)  erase_s[tid - 325] = sigm(v);
        else if (tid < 453)  wvec_s[tid - 389] = v;
        else if (tid < 457)  free_s[tid - 453] = sigm(v);
        else if (tid == 457) sc_s[1] = sigm(v);
        else if (tid == 458) sc_s[2] = sigm(v);
    }
    __syncthreads();
    // ---- phase 2b: key norms (5 waves) + mode softmaxes ----
    if (tid < 320) {
        const int w5 = tid >> 6, lane = tid & 63;
        const float v = (w5 == 0) ? wkey_s[lane] : keys_s[w5 - 1][lane];
        float s = v * v;
        #pragma unroll
        for (int m = 1; m <= 32; m <<= 1) s += __shfl_xor(s, m);
        if (lane == 0) knorm_s[w5] = fmaxf(sqrtf(s), EPSI);
    } else if (tid >= 1020) {
        const int r = tid - 1020;
        const float m0 = z_s[459 + r*3], m1 = z_s[460 + r*3], m2 = z_s[461 + r*3];
        const float mx = fmaxf(m0, fmaxf(m1, m2));
        const float e0 = expf(m0 - mx), e1 = expf(m1 - mx), e2 = expf(m2 - mx);
        const float s = e0 + e1 + e2;
        modes_s[r][0] = e0 / s; modes_s[r][1] = e1 / s; modes_s[r][2] = e2 / s;
    }
    __syncthreads();

    // ---- phase 3: retention & usage (ww_old, rw_old) ----
    if (tid < 256) {
        float ret = 1.0f;
        #pragma unroll
        for (int r = 0; r < 4; ++r) ret *= 1.0f - free_s[r] * rw_s[r][tid];
        const float un = (u_s[tid] + ww_old_s[tid] - u_s[tid] * ww_old_s[tid]) * ret;
        u_s[tid] = un;
        ws[OFF_USAGE + b * 256 + tid] = un;
    }
    __syncthreads();

    // ---- phase 4: allocation via stable lexicographic product ----
    {
        const int q = tid >> 8, n = tid & 255;
        const float un = u_s[n];
        float p = 1.0f;
        for (int m = q * 64; m < q * 64 + 64; ++m) {
            const float um = u_s[m];
            const bool lt = (um < un) || (um == un && m < n);
            p *= lt ? um : 1.0f;
        }
        Lt_s[q * 256 + n] = p;
    }
    __syncthreads();
    if (tid < 256)
        alloc_s[tid] = (1.0f - u_s[tid]) * Lt_s[tid] * Lt_s[256 + tid] * Lt_s[512 + tid] * Lt_s[768 + tid];
    __syncthreads();

    // ---- phase 5a: row norms of M (old) ----
    {
        const int n = tid >> 2, q = tid & 3;
        const float* mp = wsM + n * 64 + q * 16;
        float s = 0.0f;
        #pragma unroll
        for (int it = 0; it < 4; ++it) {
            float4 v = *(const float4*)(mp + it * 4);
            s += v.x*v.x + v.y*v.y + v.z*v.z + v.w*v.w;
        }
        s += __shfl_xor(s, 1); s += __shfl_xor(s, 2);
        if (q == 0) mnorm_s[n] = fmaxf(sqrtf(s), EPSI);
    }
    __syncthreads();
    // ---- phase 5b: write-content sim + softmax -> cw ----
    {
        const int n = tid >> 2, q = tid & 3;
        const float* mp = wsM + n * 64 + q * 16;
        float s = 0.0f;
        #pragma unroll
        for (int it = 0; it < 4; ++it) {
            float4 mv = *(const float4*)(mp + it * 4);
            float4 kv = *(const float4*)&wkey_s[q * 16 + it * 4];
            s += mv.x*kv.x + mv.y*kv.y + mv.z*kv.z + mv.w*kv.w;
        }
        s += __shfl_xor(s, 1); s += __shfl_xor(s, 2);
        if (q == 0) cw_s[n] = sc_s[0] * s / (knorm_s[0] * mnorm_s[n]);
    }
    __syncthreads();
    // softmax over cw_s[0..255]
    {
        float v = 0.0f, e = 0.0f;
        if (tid < 256) {
            v = cw_s[tid];
            float m = v;
            #pragma unroll
            for (int mm = 1; mm <= 32; mm <<= 1) m = fmaxf(m, __shfl_xor(m, mm));
            if ((tid & 63) == 0) sred_s[tid >> 6] = m;
        }
        __syncthreads();
        if (tid == 0) sc_s[4] = fmaxf(fmaxf(sred_s[0], sred_s[1]), fmaxf(sred_s[2], sred_s[3]));
        __syncthreads();
        if (tid < 256) {
            e = expf(v - sc_s[4]);
            float s2 = e;
            #pragma unroll
            for (int mm = 1; mm <= 32; mm <<= 1) s2 += __shfl_xor(s2, mm);
            if ((tid & 63) == 0) sred_s[tid >> 6] = s2;
        }
        __syncthreads();
        if (tid == 0) sc_s[5] = sred_s[0] + sred_s[1] + sred_s[2] + sred_s[3];
        __syncthreads();
        if (tid < 256) cw_s[tid] = e / sc_s[5];
    }
    __syncthreads();

    // ---- phase 6: ww, sum(ww), prec_new (prec_s keeps OLD for link) ----
    if (tid < 256) {
        const float wwn = sc_s[2] * (sc_s[1] * alloc_s[tid] + (1.0f - sc_s[1]) * cw_s[tid]);
        ww_s[tid] = wwn;
        ws[OFF_WW + b * 256 + tid] = wwn;
    }
    __syncthreads();
    if (tid < 256) {
        float s = ww_s[tid];
        #pragma unroll
        for (int mm = 1; mm <= 32; mm <<= 1) s += __shfl_xor(s, mm);
        if ((tid & 63) == 0) sred_s[tid >> 6] = s;
    }
    __syncthreads();
    if (tid == 0) sc_s[3] = sred_s[0] + sred_s[1] + sred_s[2] + sred_s[3];
    __syncthreads();
    if (tid < 256) {
        const float pn = (1.0f - sc_s[3]) * prec_s[tid] + ww_s[tid];
        prec_new_s[tid] = pn;
        ws[OFF_PREC + b * 256 + tid] = pn;
    }
    __syncthreads();

    // ---- phase 7: M update (in place, global) ----
    {
        const int n = tid >> 2, q = tid & 3;
        const float wwn = ww_s[n];
        float* mp = wsM + n * 64 + q * 16;
        #pragma unroll
        for (int it = 0; it < 4; ++it) {
            float4 m = *(const float4*)(mp + it * 4);
            const int w = q * 16 + it * 4;
            float4 er = *(const float4*)&erase_s[w];
            float4 wv = *(const float4*)&wvec_s[w];
            m.x = m.x * (1.0f - wwn * er.x) + wwn * wv.x;
            m.y = m.y * (1.0f - wwn * er.y) + wwn * wv.y;
            m.z = m.z * (1.0f - wwn * er.z) + wwn * wv.z;
            m.w = m.w * (1.0f - wwn * er.w) + wwn * wv.w;
            *(float4*)(mp + it * 4) = m;
        }
    }
    __syncthreads();

    // ---- phase 8a: row norms of M (new) ----
    {
        const int n = tid >> 2, q = tid & 3;
        const float* mp = wsM + n * 64 + q * 16;
        float s = 0.0f;
        #pragma unroll
        for (int it = 0; it < 4; ++it) {
            float4 v = *(const float4*)(mp + it * 4);
            s += v.x*v.x + v.y*v.y + v.z*v.z + v.w*v.w;
        }
        s += __shfl_xor(s, 1); s += __shfl_xor(s, 2);
        if (q == 0) mnorm_s[n] = fmaxf(sqrtf(s), EPSI);
    }
    __syncthreads();
    // ---- phase 8b: read-content sims (all 4 heads) ----
    {
        const int n = tid >> 2, q = tid & 3;
        const float* mp = wsM + n * 64 + q * 16;
        float r0=0, r1=0, r2=0, r3=0;
        #pragma unroll
        for (int it = 0; it < 4; ++it) {
            float4 m = *(const float4*)(mp + it * 4);
            const int w = q * 16 + it * 4;
            float4 k0 = *(const float4*)&keys_s[0][w];
            float4 k1 = *(const float4*)&keys_s[1][w];
            float4 k2 = *(const float4*)&keys_s[2][w];
            float4 k3 = *(const float4*)&keys_s[3][w];
            r0 += m.x*k0.x + m.y*k0.y + m.z*k0.z + m.w*k0.w;
            r1 += m.x*k1.x + m.y*k1.y + m.z*k1.z + m.w*k1.w;
            r2 += m.x*k2.x + m.y*k2.y + m.z*k2.z + m.w*k2.w;
            r3 += m.x*k3.x + m.y*k3.y + m.z*k3.z + m.w*k3.w;
        }
        #pragma unroll
        for (int mm = 1; mm <= 2; mm <<= 1) {
            r0 += __shfl_xor(r0, mm); r1 += __shfl_xor(r1, mm);
            r2 += __shfl_xor(r2, mm); r3 += __shfl_xor(r3, mm);
        }
        if (q == 0) {
            const float inv = 1.0f / mnorm_s[n];
            cr_s[0][n] = rstr_s[0] * r0 * inv / knorm_s[1];
            cr_s[1][n] = rstr_s[1] * r1 * inv / knorm_s[2];
            cr_s[2][n] = rstr_s[2] * r2 * inv / knorm_s[3];
            cr_s[3][n] = rstr_s[3] * r3 * inv / knorm_s[4];
        }
    }
    __syncthreads();
    // 4 parallel softmaxes over n (one per head)
    {
        const int r = tid >> 8, n = tid & 255;
        const float v = cr_s[r][n];
        float m = v;
        #pragma unroll
        for (int mm = 1; mm <= 32; mm <<= 1) m = fmaxf(m, __shfl_xor(m, mm));
        if ((tid & 63) == 0) sred_s[tid >> 6] = m;
        __syncthreads();
        if (tid < 4) gmax_s[tid] = fmaxf(fmaxf(sred_s[tid*4], sred_s[tid*4+1]),
                                         fmaxf(sred_s[tid*4+2], sred_s[tid*4+3]));
        __syncthreads();
        const float e = expf(v - gmax_s[r]);
        float s2 = e;
        #pragma unroll
        for (int mm = 1; mm <= 32; mm <<= 1) s2 += __shfl_xor(s2, mm);
        if ((tid & 63) == 0) sred_s[tid >> 6] = s2;
        __syncthreads();
        if (tid < 4) gsum_s[tid] = sred_s[tid*4] + sred_s[tid*4+1] + sred_s[tid*4+2] + sred_s[tid*4+3];
        __syncthreads();
        cr_s[r][n] = e / gsum_s[r];
    }
    __syncthreads();

    // ---- phase 9: link update + fw + bw (8 chunks of 32 rows) ----
    {
        const int il  = tid >> 5;        // row-in-chunk 0..31
        const int jgA = tid & 31;        // j-group; j0 = 8*jgA
        const int j0  = jgA * 8;
        float wwj[8], pj[8];
        *(float4*)&wwj[0] = *(const float4*)&ww_s[j0];
        *(float4*)&wwj[4] = *(const float4*)&ww_s[j0 + 4];
        *(float4*)&pj[0]  = *(const float4*)&prec_s[j0];
        *(float4*)&pj[4]  = *(const float4*)&prec_s[j0 + 4];
        float rwj[4][8];
        #pragma unroll
        for (int r = 0; r < 4; ++r) {
            *(float4*)&rwj[r][0] = *(const float4*)&rw_s[r][j0];
            *(float4*)&rwj[r][4] = *(const float4*)&rw_s[r][j0 + 4];
        }
        const int rB = tid >> 8, jB = tid & 255;  // passB role
        float bwacc = 0.0f;

        for (int cb = 0; cb < 8; ++cb) {
            const int i = cb * 32 + il;
            const float wwi = ww_s[i];
            float* lp = wsL + (size_t)i * 256 + j0;
            float4 o0 = *(const float4*)lp;
            float4 o1 = *(const float4*)(lp + 4);
            float ln[8] = { o0.x, o0.y, o0.z, o0.w, o1.x, o1.y, o1.z, o1.w };
            float f0=0, f1=0, f2=0, f3=0;
            #pragma unroll
            for (int e = 0; e < 8; ++e) {
                float v = (1.0f - wwi - wwj[e]) * ln[e] + wwi * pj[e];
                if (j0 + e == i) v = 0.0f;
                ln[e] = v;
                f0 += v * rwj[0][e]; f1 += v * rwj[1][e];
                f2 += v * rwj[2][e]; f3 += v * rwj[3][e];
            }
            *(float4*)lp       = make_float4(ln[0], ln[1], ln[2], ln[3]);
            *(float4*)(lp + 4) = make_float4(ln[4], ln[5], ln[6], ln[7]);
            *(float4*)&Lt_s[il * 256 + j0]     = make_float4(ln[0], ln[1], ln[2], ln[3]);
            *(float4*)&Lt_s[il * 256 + j0 + 4] = make_float4(ln[4], ln[5], ln[6], ln[7]);
            #pragma unroll
            for (int mm = 1; mm <= 16; mm <<= 1) {
                f0 += __shfl_xor(f0, mm); f1 += __shfl_xor(f1, mm);
                f2 += __shfl_xor(f2, mm); f3 += __shfl_xor(f3, mm);
            }
            if (jgA == 0) {
                fw_s[0][i] = f0; fw_s[1][i] = f1; fw_s[2][i] = f2; fw_s[3][i] = f3;
            }
            __syncthreads();   // Lt tile ready
            {
                const float* rwp = &rw_s[rB][cb * 32];
                #pragma unroll 8
                for (int ii = 0; ii < 32; ++ii)
                    bwacc += Lt_s[ii * 256 + jB] * rwp[ii];
            }
            __syncthreads();   // before next chunk overwrites Lt
        }
        bw_s[rB][jB] = bwacc;
    }
    __syncthreads();

    // ---- phase 10: rw update ----
    {
        const int r = tid >> 8, n = tid & 255;
        const float v = modes_s[r][0] * bw_s[r][n] + modes_s[r][1] * cr_s[r][n] + modes_s[r][2] * fw_s[r][n];
        rw_s[r][n] = v;
        ws[OFF_RW + b * 1024 + r * 256 + n] = v;
    }
    __syncthreads();

    // ---- phase 11: rvec = rw_new @ M_new ----
    {
        const int q = tid >> 8, r = (tid >> 6) & 3, w = tid & 63;
        float s = 0.0f;
        for (int n = q * 64; n < q * 64 + 64; ++n)
            s += rw_s[r][n] * wsM[n * 64 + w];
        Lt_s[q * 256 + r * 64 + w] = s;
    }
    __syncthreads();
    if (tid < 256) {
        const float rv = Lt_s[tid] + Lt_s[256 + tid] + Lt_s[512 + tid] + Lt_s[768 + tid];
        alloc_s[tid] = rv;  // rvec reuse
        ws[OFF_RVEC + b * 256 + tid] = rv;
    }
    __syncthreads();

    // ---- phase 12: out = hpre + rvec @ W_rout ----
    {
        const int jg = tid >> 3, kq = tid & 7;
        const int j0 = jg * 4;
        float a0=0, a1=0, a2=0, a3=0;
        const float* wb = W_rout + (size_t)(kq * 32) * 512 + j0;
        #pragma unroll 4
        for (int kk = 0; kk < 32; ++kk) {
            const float rv = alloc_s[kq * 32 + kk];
            float4 w = *(const float4*)wb; wb += 512;
            a0 += rv * w.x; a1 += rv * w.y; a2 += rv * w.z; a3 += rv * w.w;
        }
        #pragma unroll
        for (int m = 1; m <= 4; m <<= 1) {
            a0 += __shfl_xor(a0, m); a1 += __shfl_xor(a1, m);
            a2 += __shfl_xor(a2, m); a3 += __shfl_xor(a3, m);
        }
        if (kq == 0) {
            float* op = out + (size_t)t * (TB * TD) + b * TD;
            op[j0]     = hpre_s[j0]     + a0;
            op[j0 + 1] = hpre_s[j0 + 1] + a1;
            op[j0 + 2] = hpre_s[j0 + 2] + a2;
            op[j0 + 3] = hpre_s[j0 + 3] + a3;
        }
    }
}

extern "C" void kernel_launch(void* const* d_in, const int* in_sizes, int n_in,
                              void* d_out, int out_size, void* d_ws, size_t ws_size,
                              hipStream_t stream) {
    const float* emb    = (const float*)d_in[0];
    const float* Wx     = (const float*)d_in[1];
    const float* Wh     = (const float*)d_in[2];
    const float* b_lstm = (const float*)d_in[3];
    const float* W_pre  = (const float*)d_in[4];
    const float* b_pre  = (const float*)d_in[5];
    const float* W_if   = (const float*)d_in[6];
    const float* b_if   = (const float*)d_in[7];
    const float* W_rout = (const float*)d_in[8];
    float* out = (float*)d_out;
    float* ws  = (float*)d_ws;

    k_init<<<TOTAL_STATE / 256, 256, 0, stream>>>(ws);
    for (int t = 0; t < TT; ++t) {
        k_gates<<<128, 256, 0, stream>>>(emb, Wx, Wh, b_lstm, ws, t);
        k_step<<<32, 1024, 0, stream>>>(W_if, b_if, W_pre, b_pre, W_rout, ws, out, t);
    }
}

// Round 2
// 12976.689 us; speedup vs baseline: 1.6772x; 1.6772x over previous
//
#include <hip/hip_runtime.h>
#include <math.h>

// ---------------- problem constants ----------------
#define TN   256     // memory slots
#define TWM  64      // word size
#define TR   4       // read heads
#define TH   512     // hidden
#define TD   512     // input dim
#define TT   128     // time steps
#define TB   32      // batch
#define IFACE 471
#define EPSI 1e-6f

// ---------------- workspace layout (floats) ----------------
#define OFF_H      0          // 2 x 32*512 ping-pong by t parity
#define OFF_C      32768      // 32*512
#define OFF_M      49152      // 32*256*64
#define OFF_USAGE  573440     // 32*256
#define OFF_RW     581632     // 32*4*256
#define OFF_WW     614400     // 32*256
#define OFF_PREC   622592     // 32*256
#define OFF_LINK   630784     // 32*256*256
#define OFF_RVEC   2727936    // 32*256
#define OFF_ZP     2736128    // 4 x 32 x 480 z partials
#define TOTAL_STATE 2797568

__device__ __forceinline__ float sigm(float x)  { return 1.0f / (1.0f + expf(-x)); }
__device__ __forceinline__ float softpl(float x){ return x > 20.0f ? x : log1pf(expf(x)); }

// ---------------- init: zero state, M = EPS ----------------
__global__ void k_init(float* ws) {
    int idx = blockIdx.x * 256 + threadIdx.x;
    if (idx < TOTAL_STATE)
        ws[idx] = (idx >= OFF_M && idx < OFF_M + TB*TN*TWM) ? EPSI : 0.0f;
}

// ---------------- kernel A: gates GEMM + LSTM pointwise ----------------
// grid 128 blocks (4 hidden units each, 16 gate-cols), 512 threads, 16-way k-split.
__global__ __launch_bounds__(512) void k_gates(
    const float* __restrict__ emb, const float* __restrict__ Wx,
    const float* __restrict__ Wh,  const float* __restrict__ b_lstm,
    float* __restrict__ ws, int t)
{
    __shared__ __align__(16) float smem[16384];
    const int tid = threadIdx.x;
    const int u0  = blockIdx.x * 4;
    const int cg  = tid & 3;          // gate index
    const int bg  = (tid >> 2) & 7;   // batch group (4 batches)
    const int ks  = tid >> 5;         // k-split 0..15
    const int col0 = cg * 512 + u0;
    const float* hbuf = ws + OFF_H + (t & 1) * (TB * TH);

    float acc[4][4] = {};

    for (int tile = 0; tile < 5; ++tile) {
        const int T0 = tile * 256;
        // ---- cooperative act-tile load: smem[k_local][b], 256 k x 32 b ----
        {
            const int b = tid & 31, kf4 = tid >> 5;   // kf4 0..15
            #pragma unroll
            for (int i = 0; i < 4; ++i) {
                const int kf = kf4 * 4 + i;           // 0..63 float4 chunks
                const int kl = kf * 4;
                const int k  = T0 + kl;
                const float* src;
                if (k < 512)      src = emb + (size_t)t * (TB*TD) + b * TD + k;
                else if (k < 768) src = ws + OFF_RVEC + b * 256 + (k - 512);
                else              src = hbuf + b * TH + (k - 768);
                float4 v = *(const float4*)src;
                smem[(kl+0)*32 + b] = v.x;
                smem[(kl+1)*32 + b] = v.y;
                smem[(kl+2)*32 + b] = v.z;
                smem[(kl+3)*32 + b] = v.w;
            }
        }
        __syncthreads();
        // ---- compute this tile's 16 k's for this thread ----
        {
            const int k0 = T0 + ks * 16;
            const float* wp = (k0 < 768 ? Wx + (size_t)k0 * 2048
                                        : Wh + (size_t)(k0 - 768) * 2048) + col0;
            const float* ap = &smem[(ks * 16) * 32 + bg * 4];
            #pragma unroll 8
            for (int kk = 0; kk < 16; ++kk) {
                float4 wv = *(const float4*)wp; wp += 2048;
                float4 av = *(const float4*)ap; ap += 32;
                acc[0][0] += wv.x*av.x; acc[0][1] += wv.x*av.y; acc[0][2] += wv.x*av.z; acc[0][3] += wv.x*av.w;
                acc[1][0] += wv.y*av.x; acc[1][1] += wv.y*av.y; acc[1][2] += wv.y*av.z; acc[1][3] += wv.y*av.w;
                acc[2][0] += wv.z*av.x; acc[2][1] += wv.z*av.y; acc[2][2] += wv.z*av.z; acc[2][3] += wv.z*av.w;
                acc[3][0] += wv.w*av.x; acc[3][1] += wv.w*av.y; acc[3][2] += wv.w*av.z; acc[3][3] += wv.w*av.w;
            }
        }
        __syncthreads();
    }

    // ---- write k-split partials to LDS [ks][512] at offset 8192 ----
    {
        const int rbase = 8192 + ks * 512 + (cg * 8 + bg) * 16;
        *(float4*)&smem[rbase + 0]  = make_float4(acc[0][0], acc[0][1], acc[0][2], acc[0][3]);
        *(float4*)&smem[rbase + 4]  = make_float4(acc[1][0], acc[1][1], acc[1][2], acc[1][3]);
        *(float4*)&smem[rbase + 8]  = make_float4(acc[2][0], acc[2][1], acc[2][2], acc[2][3]);
        *(float4*)&smem[rbase + 12] = make_float4(acc[3][0], acc[3][1], acc[3][2], acc[3][3]);
    }
    __syncthreads();
    // ---- reduce 16 partials, add bias, store gates to smem[0..511] ----
    {
        const int o = tid;
        float s = 0.0f;
        #pragma unroll
        for (int kq = 0; kq < 16; ++kq) s += smem[8192 + kq * 512 + o];
        const int ocg = o >> 7, obg = (o >> 4) & 7, odu = (o >> 2) & 3, obb = o & 3;
        s += b_lstm[ocg * 512 + u0 + odu];
        smem[(ocg * 4 + odu) * 32 + (obg * 4 + obb)] = s;
    }
    __syncthreads();
    // ---- LSTM pointwise for 4 units x 32 batches ----
    if (tid < 128) {
        const int du = tid >> 5, b = tid & 31;
        const float ig = smem[(0  + du) * 32 + b];
        const float fg = smem[(4  + du) * 32 + b];
        const float gg = smem[(8  + du) * 32 + b];
        const float og = smem[(12 + du) * 32 + b];
        const int ci = b * TH + u0 + du;
        const float cold = ws[OFF_C + ci];
        const float cn = sigm(fg) * cold + sigm(ig) * tanhf(gg);
        const float hn = sigm(og) * tanhf(cn);
        ws[OFF_C + ci] = cn;
        ws[OFF_H + ((t + 1) & 1) * (TB * TH) + ci] = hn;
    }
}

// ---------------- kernel A2: iface GEMV partials + out(t-1) ----------------
// grid 128 blocks = (q 0..3) x (b 0..31), 512 threads.
// job1 (t<128): zp[q][b][col] = sum_{k in q-quarter} h(t+1)[k] * W_if[k][col]  (+b_if if q==0)
// job2 (t>0):   out(t-1)[b][q*128..+128) = h(t)@W_pre + b_pre + rvec(t-1)@W_rout
__global__ __launch_bounds__(512) void k_iface(
    const float* __restrict__ W_if, const float* __restrict__ b_if,
    const float* __restrict__ W_pre, const float* __restrict__ b_pre,
    const float* __restrict__ W_rout,
    float* __restrict__ ws, float* __restrict__ out, int t)
{
    __shared__ __align__(16) float h1_s[128];
    __shared__ __align__(16) float act_s[768];
    __shared__ __align__(16) float red_s[4][128];
    const int tid = threadIdx.x;
    const int q = blockIdx.x >> 5;
    const int b = blockIdx.x & 31;

    // stage
    if (t < TT && tid < 32)
        *(float4*)&h1_s[tid*4] = *(const float4*)&ws[OFF_H + ((t+1)&1)*(TB*TH) + b*TH + q*128 + tid*4];
    if (t > 0 && tid >= 64 && tid < 256) {
        const int i = tid - 64;           // 0..191 -> 768 floats
        const int k0 = i * 4;
        const float* src = (k0 < 512) ? &ws[OFF_H + (t&1)*(TB*TH) + b*TH + k0]
                                      : &ws[OFF_RVEC + b*256 + (k0 - 512)];
        *(float4*)&act_s[k0] = *(const float4*)src;
    }
    __syncthreads();

    // job1: z partial
    if (t < TT && tid < IFACE) {
        const int col = tid;
        float acc = (q == 0) ? b_if[col] : 0.0f;
        const float* wb = W_if + (size_t)(q * 128) * IFACE + col;
        #pragma unroll 8
        for (int kk = 0; kk < 128; ++kk) {
            acc += h1_s[kk] * wb[0];
            wb += IFACE;
        }
        ws[OFF_ZP + ((size_t)q * 32 + b) * 480 + col] = acc;
    }

    // job2: out(t-1) columns [q*128, q*128+128)
    if (t > 0) {
        const int c0 = q * 128;
        const int col = c0 + (tid & 127);
        const int kq2 = tid >> 7;          // 0..3, k range 192 each
        float acc = 0.0f;
        #pragma unroll 4
        for (int kk = kq2 * 192; kk < kq2 * 192 + 192; ++kk) {
            const float w = (kk < 512) ? W_pre[(size_t)kk * 512 + col]
                                       : W_rout[(size_t)(kk - 512) * 512 + col];
            acc += act_s[kk] * w;
        }
        red_s[kq2][tid & 127] = acc;
        __syncthreads();
        if (tid < 128) {
            const float s = red_s[0][tid] + red_s[1][tid] + red_s[2][tid] + red_s[3][tid]
                          + b_pre[c0 + tid];
            out[(size_t)(t - 1) * (TB * TD) + b * TD + c0 + tid] = s;
        }
    }
}

// ---------------- kernel B: per-batch DNC memory step ----------------
// grid 32 blocks (one per batch), 512 threads.
__global__ __launch_bounds__(512, 2) void k_step(
    float* __restrict__ ws, int t)
{
    __shared__ __align__(16) float z_s[472];
    __shared__ __align__(16) float rw_s[4][256];
    __shared__ __align__(16) float ww_old_s[256];
    __shared__ __align__(16) float ww_s[256];
    __shared__ __align__(16) float u_s[256];
    __shared__ __align__(16) float prec_s[256];
    __shared__ __align__(16) float alloc_s[256];
    __shared__ __align__(16) float cw_s[256];
    __shared__ __align__(16) float cr_s[4][256];
    __shared__ __align__(16) float fw_s[4][256];
    __shared__ __align__(16) float bw_s[4][256];
    __shared__ __align__(16) float keys_s[4][64];
    __shared__ __align__(16) float wkey_s[64];
    __shared__ __align__(16) float erase_s[64];
    __shared__ __align__(16) float wvec_s[64];
    __shared__ __align__(16) float mnorm_s[256];
    __shared__ __align__(16) float rstr_s[4];
    __shared__ __align__(16) float free_s[4];
    __shared__ __align__(16) float modes_s[4][3];
    __shared__ __align__(16) float knorm_s[8];
    __shared__ __align__(16) float sredA_s[8];
    __shared__ __align__(16) float sredB_s[8];
    __shared__ __align__(16) float sc_s[8];        // 0 wstr, 1 ag, 2 wg, 3 sumww, 4 gmax, 5 gsum
    __shared__ __align__(16) float gmax_s[4];
    __shared__ __align__(16) float gsum_s[4];
    __shared__ __align__(16) float Lt_s[32 * 256]; // link chunk tile / scratch

    const int b   = blockIdx.x;
    const int tid = threadIdx.x;
    float* wsM = ws + OFF_M + b * (TN * TWM);
    float* wsL = ws + OFF_LINK + (size_t)b * (TN * TN);

    // ---- phase 0: stage state into LDS + sum z partials ----
    if (tid < 256)       { *(float4*)&((float*)rw_s)[tid*4] = *(const float4*)&ws[OFF_RW + b*1024 + tid*4]; }
    else if (tid < 320)  { const int i = tid-256; *(float4*)&ww_old_s[i*4] = *(const float4*)&ws[OFF_WW + b*256 + i*4]; }
    else if (tid < 384)  { const int i = tid-320; *(float4*)&u_s[i*4]      = *(const float4*)&ws[OFF_USAGE + b*256 + i*4]; }
    else if (tid < 448)  { const int i = tid-384; *(float4*)&prec_s[i*4]   = *(const float4*)&ws[OFF_PREC + b*256 + i*4]; }
    if (tid < IFACE) {
        const size_t zb = OFF_ZP + (size_t)b * 480 + tid;
        z_s[tid] = ws[zb] + ws[zb + 32*480] + ws[zb + 64*480] + ws[zb + 96*480];
    }
    __syncthreads();

    // ---- phase 2a: parse interface vector ----
    if (tid < IFACE) {
        const float v = z_s[tid];
        if (tid < 256)       keys_s[tid >> 6][tid & 63] = v;
        else if (tid < 260)  rstr_s[tid - 256] = 1.0f + softpl(v);
        else if (tid < 324)  wkey_s[tid - 260] = v;
        else if (tid == 324) sc_s[0] = 1.0f + softpl(v);
        else if (tid < 389)  erase_s[tid - 325] = sigm(v);
        else if (tid < 453)  wvec_s[tid - 389] = v;
        else if (tid < 457)  free_s[tid - 453] = sigm(v);
        else if (tid == 457) sc_s[1] = sigm(v);
        else if (tid == 458) sc_s[2] = sigm(v);
    }
    __syncthreads();
    // ---- phase 2b: key norms (5 waves) + mode softmaxes ----
    if (tid < 320) {
        const int w5 = tid >> 6, lane = tid & 63;
        const float v = (w5 == 0) ? wkey_s[lane] : keys_s[w5 - 1][lane];
        float s = v * v;
        #pragma unroll
        for (int m = 1; m <= 32; m <<= 1) s += __shfl_xor(s, m);
        if (lane == 0) knorm_s[w5] = fmaxf(sqrtf(s), EPSI);
    } else if (tid >= 508) {
        const int r = tid - 508;
        const float m0 = z_s[459 + r*3], m1 = z_s[460 + r*3], m2 = z_s[461 + r*3];
        const float mx = fmaxf(m0, fmaxf(m1, m2));
        const float e0 = expf(m0 - mx), e1 = expf(m1 - mx), e2 = expf(m2 - mx);
        const float s = e0 + e1 + e2;
        modes_s[r][0] = e0 / s; modes_s[r][1] = e1 / s; modes_s[r][2] = e2 / s;
    }
    __syncthreads();

    // ---- phase 3: retention & usage ----
    if (tid < 256) {
        float ret = 1.0f;
        #pragma unroll
        for (int r = 0; r < 4; ++r) ret *= 1.0f - free_s[r] * rw_s[r][tid];
        const float un = (u_s[tid] + ww_old_s[tid] - u_s[tid] * ww_old_s[tid]) * ret;
        u_s[tid] = un;
        ws[OFF_USAGE + b * 256 + tid] = un;
    }
    __syncthreads();

    // ---- phase 4: allocation via stable lexicographic product ----
    {
        const int q = tid >> 8, n = tid & 255;
        const float un = u_s[n];
        float p = 1.0f;
        #pragma unroll 8
        for (int m = q * 128; m < q * 128 + 128; ++m) {
            const float um = u_s[m];
            const bool lt = (um < un) || (um == un && m < n);
            p *= lt ? um : 1.0f;
        }
        Lt_s[q * 256 + n] = p;
    }
    __syncthreads();
    if (tid < 256)
        alloc_s[tid] = (1.0f - u_s[tid]) * Lt_s[tid] * Lt_s[256 + tid];
    __syncthreads();

    // ---- phase 5a: row norms of M (old) ----
    {
        const int n = tid >> 1, q = tid & 1;
        const float* mp = wsM + n * 64 + q * 32;
        float s = 0.0f;
        #pragma unroll
        for (int it = 0; it < 8; ++it) {
            float4 v = *(const float4*)(mp + it * 4);
            s += v.x*v.x + v.y*v.y + v.z*v.z + v.w*v.w;
        }
        s += __shfl_xor(s, 1);
        if (q == 0) mnorm_s[n] = fmaxf(sqrtf(s), EPSI);
    }
    __syncthreads();
    // ---- phase 5b: write-content sim -> cw ----
    {
        const int n = tid >> 1, q = tid & 1;
        const float* mp = wsM + n * 64 + q * 32;
        float s = 0.0f;
        #pragma unroll
        for (int it = 0; it < 8; ++it) {
            float4 mv = *(const float4*)(mp + it * 4);
            float4 kv = *(const float4*)&wkey_s[q * 32 + it * 4];
            s += mv.x*kv.x + mv.y*kv.y + mv.z*kv.z + mv.w*kv.w;
        }
        s += __shfl_xor(s, 1);
        if (q == 0) cw_s[n] = sc_s[0] * s / (knorm_s[0] * mnorm_s[n]);
    }
    __syncthreads();
    // softmax over cw_s[0..255]
    {
        float v = 0.0f, e = 0.0f;
        if (tid < 256) {
            v = cw_s[tid];
            float m = v;
            #pragma unroll
            for (int mm = 1; mm <= 32; mm <<= 1) m = fmaxf(m, __shfl_xor(m, mm));
            if ((tid & 63) == 0) sredA_s[tid >> 6] = m;
        }
        __syncthreads();
        if (tid == 0) sc_s[4] = fmaxf(fmaxf(sredA_s[0], sredA_s[1]), fmaxf(sredA_s[2], sredA_s[3]));
        __syncthreads();
        if (tid < 256) {
            e = expf(v - sc_s[4]);
            float s2 = e;
            #pragma unroll
            for (int mm = 1; mm <= 32; mm <<= 1) s2 += __shfl_xor(s2, mm);
            if ((tid & 63) == 0) sredA_s[tid >> 6] = s2;
        }
        __syncthreads();
        if (tid == 0) sc_s[5] = sredA_s[0] + sredA_s[1] + sredA_s[2] + sredA_s[3];
        __syncthreads();
        if (tid < 256) cw_s[tid] = e / sc_s[5];
    }
    __syncthreads();

    // ---- phase 6: ww, sum(ww), prec_new (prec_s keeps OLD for link) ----
    if (tid < 256) {
        const float wwn = sc_s[2] * (sc_s[1] * alloc_s[tid] + (1.0f - sc_s[1]) * cw_s[tid]);
        ww_s[tid] = wwn;
        ws[OFF_WW + b * 256 + tid] = wwn;
    }
    __syncthreads();
    if (tid < 256) {
        float s = ww_s[tid];
        #pragma unroll
        for (int mm = 1; mm <= 32; mm <<= 1) s += __shfl_xor(s, mm);
        if ((tid & 63) == 0) sredA_s[tid >> 6] = s;
    }
    __syncthreads();
    if (tid == 0) sc_s[3] = sredA_s[0] + sredA_s[1] + sredA_s[2] + sredA_s[3];
    __syncthreads();
    if (tid < 256) {
        const float pn = (1.0f - sc_s[3]) * prec_s[tid] + ww_s[tid];
        ws[OFF_PREC + b * 256 + tid] = pn;
    }

    // ---- phase 7: M update (in place) ----
    {
        const int n = tid >> 1, q = tid & 1;
        const float wwn = ww_s[n];
        float* mp = wsM + n * 64 + q * 32;
        #pragma unroll
        for (int it = 0; it < 8; ++it) {
            float4 m = *(const float4*)(mp + it * 4);
            const int w = q * 32 + it * 4;
            float4 er = *(const float4*)&erase_s[w];
            float4 wv = *(const float4*)&wvec_s[w];
            m.x = m.x * (1.0f - wwn * er.x) + wwn * wv.x;
            m.y = m.y * (1.0f - wwn * er.y) + wwn * wv.y;
            m.z = m.z * (1.0f - wwn * er.z) + wwn * wv.z;
            m.w = m.w * (1.0f - wwn * er.w) + wwn * wv.w;
            *(float4*)(mp + it * 4) = m;
        }
    }
    __syncthreads();

    // ---- phase 8a: row norms of M (new) ----
    {
        const int n = tid >> 1, q = tid & 1;
        const float* mp = wsM + n * 64 + q * 32;
        float s = 0.0f;
        #pragma unroll
        for (int it = 0; it < 8; ++it) {
            float4 v = *(const float4*)(mp + it * 4);
            s += v.x*v.x + v.y*v.y + v.z*v.z + v.w*v.w;
        }
        s += __shfl_xor(s, 1);
        if (q == 0) mnorm_s[n] = fmaxf(sqrtf(s), EPSI);
    }
    __syncthreads();
    // ---- phase 8b: read-content sims (4 heads) ----
    {
        const int n = tid >> 1, q = tid & 1;
        const float* mp = wsM + n * 64 + q * 32;
        float r0=0, r1=0, r2=0, r3=0;
        #pragma unroll
        for (int it = 0; it < 8; ++it) {
            float4 m = *(const float4*)(mp + it * 4);
            const int w = q * 32 + it * 4;
            float4 k0 = *(const float4*)&keys_s[0][w];
            float4 k1 = *(const float4*)&keys_s[1][w];
            float4 k2 = *(const float4*)&keys_s[2][w];
            float4 k3 = *(const float4*)&keys_s[3][w];
            r0 += m.x*k0.x + m.y*k0.y + m.z*k0.z + m.w*k0.w;
            r1 += m.x*k1.x + m.y*k1.y + m.z*k1.z + m.w*k1.w;
            r2 += m.x*k2.x + m.y*k2.y + m.z*k2.z + m.w*k2.w;
            r3 += m.x*k3.x + m.y*k3.y + m.z*k3.z + m.w*k3.w;
        }
        r0 += __shfl_xor(r0, 1); r1 += __shfl_xor(r1, 1);
        r2 += __shfl_xor(r2, 1); r3 += __shfl_xor(r3, 1);
        if (q == 0) {
            const float inv = 1.0f / mnorm_s[n];
            cr_s[0][n] = rstr_s[0] * r0 * inv / knorm_s[1];
            cr_s[1][n] = rstr_s[1] * r1 * inv / knorm_s[2];
            cr_s[2][n] = rstr_s[2] * r2 * inv / knorm_s[3];
            cr_s[3][n] = rstr_s[3] * r3 * inv / knorm_s[4];
        }
    }
    __syncthreads();
    // 4 softmaxes over n: thread handles heads rr and rr+2 at column n
    {
        const int rr = tid >> 8, n = tid & 255, wv = tid >> 6, lane = tid & 63;
        float v0 = cr_s[rr][n], v1 = cr_s[rr + 2][n];
        float m0 = v0, m1 = v1;
        #pragma unroll
        for (int mm = 1; mm <= 32; mm <<= 1) {
            m0 = fmaxf(m0, __shfl_xor(m0, mm));
            m1 = fmaxf(m1, __shfl_xor(m1, mm));
        }
        if (lane == 0) { sredA_s[wv] = m0; sredB_s[wv] = m1; }
        __syncthreads();
        if (tid < 4) {
            const float* base = (tid & 2) ? sredB_s : sredA_s;
            const int off = (tid & 1) * 4;
            gmax_s[tid] = fmaxf(fmaxf(base[off], base[off+1]), fmaxf(base[off+2], base[off+3]));
        }
        __syncthreads();
        const float e0 = expf(v0 - gmax_s[rr]);
        const float e1 = expf(v1 - gmax_s[rr + 2]);
        float s0 = e0, s1 = e1;
        #pragma unroll
        for (int mm = 1; mm <= 32; mm <<= 1) {
            s0 += __shfl_xor(s0, mm); s1 += __shfl_xor(s1, mm);
        }
        if (lane == 0) { sredA_s[wv] = s0; sredB_s[wv] = s1; }
        __syncthreads();
        if (tid < 4) {
            const float* base = (tid & 2) ? sredB_s : sredA_s;
            const int off = (tid & 1) * 4;
            gsum_s[tid] = base[off] + base[off+1] + base[off+2] + base[off+3];
        }
        __syncthreads();
        cr_s[rr][n]     = e0 / gsum_s[rr];
        cr_s[rr + 2][n] = e1 / gsum_s[rr + 2];
    }
    __syncthreads();

    // ---- phase 9: link update + fw + bw (8 chunks of 32 rows, 2 half-rows/thread) ----
    {
        const int il5 = tid >> 5;        // 0..15
        const int jg  = tid & 31;
        const int j0  = jg * 8;
        float wwj[8], pj[8], rwj0[8], rwj1[8], rwj2[8], rwj3[8];
        *(float4*)&wwj[0] = *(const float4*)&ww_s[j0];
        *(float4*)&wwj[4] = *(const float4*)&ww_s[j0 + 4];
        *(float4*)&pj[0]  = *(const float4*)&prec_s[j0];
        *(float4*)&pj[4]  = *(const float4*)&prec_s[j0 + 4];
        *(float4*)&rwj0[0] = *(const float4*)&rw_s[0][j0]; *(float4*)&rwj0[4] = *(const float4*)&rw_s[0][j0+4];
        *(float4*)&rwj1[0] = *(const float4*)&rw_s[1][j0]; *(float4*)&rwj1[4] = *(const float4*)&rw_s[1][j0+4];
        *(float4*)&rwj2[0] = *(const float4*)&rw_s[2][j0]; *(float4*)&rwj2[4] = *(const float4*)&rw_s[2][j0+4];
        *(float4*)&rwj3[0] = *(const float4*)&rw_s[3][j0]; *(float4*)&rwj3[4] = *(const float4*)&rw_s[3][j0+4];
        const int rB = tid >> 8, jB = tid & 255;
        float bw0 = 0.0f, bw1 = 0.0f;

        for (int cb = 0; cb < 8; ++cb) {
            #pragma unroll
            for (int half = 0; half < 2; ++half) {
                const int ric = il5 + half * 16;     // row in chunk 0..31
                const int i = cb * 32 + ric;
                const float wwi = ww_s[i];
                float* lp = wsL + (size_t)i * 256 + j0;
                float4 o0 = *(const float4*)lp;
                float4 o1 = *(const float4*)(lp + 4);
                float ln[8] = { o0.x, o0.y, o0.z, o0.w, o1.x, o1.y, o1.z, o1.w };
                float f0=0, f1=0, f2=0, f3=0;
                #pragma unroll
                for (int e = 0; e < 8; ++e) {
                    float v = (1.0f - wwi - wwj[e]) * ln[e] + wwi * pj[e];
                    if (j0 + e == i) v = 0.0f;
                    ln[e] = v;
                    f0 += v * rwj0[e]; f1 += v * rwj1[e];
                    f2 += v * rwj2[e]; f3 += v * rwj3[e];
                }
                *(float4*)lp       = make_float4(ln[0], ln[1], ln[2], ln[3]);
                *(float4*)(lp + 4) = make_float4(ln[4], ln[5], ln[6], ln[7]);
                *(float4*)&Lt_s[ric * 256 + j0]     = make_float4(ln[0], ln[1], ln[2], ln[3]);
                *(float4*)&Lt_s[ric * 256 + j0 + 4] = make_float4(ln[4], ln[5], ln[6], ln[7]);
                #pragma unroll
                for (int mm = 1; mm <= 16; mm <<= 1) {
                    f0 += __shfl_xor(f0, mm); f1 += __shfl_xor(f1, mm);
                    f2 += __shfl_xor(f2, mm); f3 += __shfl_xor(f3, mm);
                }
                if (jg == 0) {
                    fw_s[0][i] = f0; fw_s[1][i] = f1; fw_s[2][i] = f2; fw_s[3][i] = f3;
                }
            }
            __syncthreads();   // Lt tile ready
            {
                const float* rwpA = &rw_s[rB][cb * 32];
                const float* rwpB = &rw_s[rB + 2][cb * 32];
                #pragma unroll 8
                for (int ii = 0; ii < 32; ++ii) {
                    const float v = Lt_s[ii * 256 + jB];
                    bw0 += v * rwpA[ii];
                    bw1 += v * rwpB[ii];
                }
            }
            __syncthreads();   // before next chunk overwrites Lt
        }
        bw_s[rB][jB] = bw0;
        bw_s[rB + 2][jB] = bw1;
    }
    __syncthreads();

    // ---- phase 10: rw update ----
    {
        const int rr = tid >> 8, n = tid & 255;
        #pragma unroll
        for (int p = 0; p < 2; ++p) {
            const int r = rr + 2 * p;
            const float v = modes_s[r][0] * bw_s[r][n] + modes_s[r][1] * cr_s[r][n] + modes_s[r][2] * fw_s[r][n];
            rw_s[r][n] = v;
            ws[OFF_RW + b * 1024 + r * 256 + n] = v;
        }
    }
    __syncthreads();

    // ---- phase 11: rvec = rw_new @ M_new ----
    {
        const int q = tid >> 8, r = (tid >> 6) & 3, w = tid & 63;
        float s = 0.0f;
        #pragma unroll 4
        for (int n = q * 128; n < q * 128 + 128; ++n)
            s += rw_s[r][n] * wsM[n * 64 + w];
        Lt_s[q * 256 + r * 64 + w] = s;
    }
    __syncthreads();
    if (tid < 256)
        ws[OFF_RVEC + b * 256 + tid] = Lt_s[tid] + Lt_s[256 + tid];
}

extern "C" void kernel_launch(void* const* d_in, const int* in_sizes, int n_in,
                              void* d_out, int out_size, void* d_ws, size_t ws_size,
                              hipStream_t stream) {
    const float* emb    = (const float*)d_in[0];
    const float* Wx     = (const float*)d_in[1];
    const float* Wh     = (const float*)d_in[2];
    const float* b_lstm = (const float*)d_in[3];
    const float* W_pre  = (const float*)d_in[4];
    const float* b_pre  = (const float*)d_in[5];
    const float* W_if   = (const float*)d_in[6];
    const float* b_if   = (const float*)d_in[7];
    const float* W_rout = (const float*)d_in[8];
    float* out = (float*)d_out;
    float* ws  = (float*)d_ws;

    k_init<<<(TOTAL_STATE + 255) / 256, 256, 0, stream>>>(ws);
    for (int t = 0; t < TT; ++t) {
        k_gates<<<128, 512, 0, stream>>>(emb, Wx, Wh, b_lstm, ws, t);
        k_iface<<<128, 512, 0, stream>>>(W_if, b_if, W_pre, b_pre, W_rout, ws, out, t);
        k_step<<<32, 512, 0, stream>>>(ws, t);
    }
    // out(127)
    k_iface<<<128, 512, 0, stream>>>(W_if, b_if, W_pre, b_pre, W_rout, ws, out, TT);
}

// Round 3
// 10066.238 us; speedup vs baseline: 2.1621x; 1.2891x over previous
//
#include <hip/hip_runtime.h>
#include <math.h>

// ---------------- problem constants ----------------
#define TN   256
#define TWM  64
#define TR   4
#define TH   512
#define TD   512
#define TT   128
#define TB   32
#define IFACE 471
#define EPSI 1e-6f

// ---------------- workspace layout (floats) ----------------
#define OFF_H      0          // 2 x 32*512 ping-pong
#define OFF_C      32768
#define OFF_M      49152      // 32*256*64
#define OFF_USAGE  573440
#define OFF_RW     581632     // 32*4*256
#define OFF_WW     614400
#define OFF_PRECA  622592     // prec ping
#define OFF_PRECB  630784     // prec pong
#define OFF_LINK   638976     // 32*256*256
#define OFF_RVEC   2736128
#define OFF_MNORM  2744320    // 32*256 row norms of current M
#define OFF_ZP     2752512    // 16 x 32 x 480 z partials
#define OFF_PARSE  2998272    // 32 x 448 parsed interface
#define OFF_CRS    3012608    // 32 x 4 x 256 cr logits
#define OFF_FW     3045376    // 32 x 4 x 256
#define OFF_BWP    3078144    // 256 x 4 x 256 bw chunk partials
#define TOTAL_STATE 3340288

__device__ __forceinline__ float sigm(float x)  { return 1.0f / (1.0f + expf(-x)); }
__device__ __forceinline__ float softpl(float x){ return x > 20.0f ? x : log1pf(expf(x)); }

// ---------------- init ----------------
__global__ void k_init(float* ws) {
    int idx = blockIdx.x * 256 + threadIdx.x;
    if (idx >= TOTAL_STATE) return;
    float v = 0.0f;
    if (idx >= OFF_M && idx < OFF_M + TB*TN*TWM) v = EPSI;
    if (idx >= OFF_MNORM && idx < OFF_MNORM + TB*TN) v = 8e-6f;  // sqrt(64*EPS^2)
    ws[idx] = v;
}

// ---------------- kernel 1: gates GEMM + LSTM pointwise ----------------
__global__ __launch_bounds__(512) void k_gates(
    const float* __restrict__ emb, const float* __restrict__ Wx,
    const float* __restrict__ Wh,  const float* __restrict__ b_lstm,
    float* __restrict__ ws, int t)
{
    __shared__ __align__(16) float smem[16384];
    const int tid = threadIdx.x;
    const int u0  = blockIdx.x * 4;
    const int cg  = tid & 3;
    const int bg  = (tid >> 2) & 7;
    const int ks  = tid >> 5;
    const int col0 = cg * 512 + u0;
    const float* hbuf = ws + OFF_H + (t & 1) * (TB * TH);

    float acc[4][4] = {};

    for (int tile = 0; tile < 5; ++tile) {
        const int T0 = tile * 256;
        {
            const int b = tid & 31, kf4 = tid >> 5;
            #pragma unroll
            for (int i = 0; i < 4; ++i) {
                const int kf = kf4 * 4 + i;
                const int kl = kf * 4;
                const int k  = T0 + kl;
                const float* src;
                if (k < 512)      src = emb + (size_t)t * (TB*TD) + b * TD + k;
                else if (k < 768) src = ws + OFF_RVEC + b * 256 + (k - 512);
                else              src = hbuf + b * TH + (k - 768);
                float4 v = *(const float4*)src;
                smem[(kl+0)*32 + b] = v.x;
                smem[(kl+1)*32 + b] = v.y;
                smem[(kl+2)*32 + b] = v.z;
                smem[(kl+3)*32 + b] = v.w;
            }
        }
        __syncthreads();
        {
            const int k0 = T0 + ks * 16;
            const float* wp = (k0 < 768 ? Wx + (size_t)k0 * 2048
                                        : Wh + (size_t)(k0 - 768) * 2048) + col0;
            const float* ap = &smem[(ks * 16) * 32 + bg * 4];
            #pragma unroll 8
            for (int kk = 0; kk < 16; ++kk) {
                float4 wv = *(const float4*)wp; wp += 2048;
                float4 av = *(const float4*)ap; ap += 32;
                acc[0][0] += wv.x*av.x; acc[0][1] += wv.x*av.y; acc[0][2] += wv.x*av.z; acc[0][3] += wv.x*av.w;
                acc[1][0] += wv.y*av.x; acc[1][1] += wv.y*av.y; acc[1][2] += wv.y*av.z; acc[1][3] += wv.y*av.w;
                acc[2][0] += wv.z*av.x; acc[2][1] += wv.z*av.y; acc[2][2] += wv.z*av.z; acc[2][3] += wv.z*av.w;
                acc[3][0] += wv.w*av.x; acc[3][1] += wv.w*av.y; acc[3][2] += wv.w*av.z; acc[3][3] += wv.w*av.w;
            }
        }
        __syncthreads();
    }

    {
        const int rbase = 8192 + ks * 512 + (cg * 8 + bg) * 16;
        *(float4*)&smem[rbase + 0]  = make_float4(acc[0][0], acc[0][1], acc[0][2], acc[0][3]);
        *(float4*)&smem[rbase + 4]  = make_float4(acc[1][0], acc[1][1], acc[1][2], acc[1][3]);
        *(float4*)&smem[rbase + 8]  = make_float4(acc[2][0], acc[2][1], acc[2][2], acc[2][3]);
        *(float4*)&smem[rbase + 12] = make_float4(acc[3][0], acc[3][1], acc[3][2], acc[3][3]);
    }
    __syncthreads();
    {
        const int o = tid;
        float s = 0.0f;
        #pragma unroll
        for (int kq = 0; kq < 16; ++kq) s += smem[8192 + kq * 512 + o];
        const int ocg = o >> 7, obg = (o >> 4) & 7, odu = (o >> 2) & 3, obb = o & 3;
        s += b_lstm[ocg * 512 + u0 + odu];
        smem[(ocg * 4 + odu) * 32 + (obg * 4 + obb)] = s;
    }
    __syncthreads();
    if (tid < 128) {
        const int du = tid >> 5, b = tid & 31;
        const float ig = smem[(0  + du) * 32 + b];
        const float fg = smem[(4  + du) * 32 + b];
        const float gg = smem[(8  + du) * 32 + b];
        const float og = smem[(12 + du) * 32 + b];
        const int ci = b * TH + u0 + du;
        const float cold = ws[OFF_C + ci];
        const float cn = sigm(fg) * cold + sigm(ig) * tanhf(gg);
        const float hn = sigm(og) * tanhf(cn);
        ws[OFF_C + ci] = cn;
        ws[OFF_H + ((t + 1) & 1) * (TB * TH) + ci] = hn;
    }
}

// ---------------- kernel 2: iface z partials + out(t-1), 4 batches/block ----------------
// grid 128 = q(4) x s(4) x bg(8). 512 threads.
__global__ __launch_bounds__(512) void k_iface(
    const float* __restrict__ W_if,
    const float* __restrict__ W_pre, const float* __restrict__ b_pre,
    const float* __restrict__ W_rout,
    float* __restrict__ ws, float* __restrict__ out, int t)
{
    __shared__ __align__(16) float h1_s[128];      // 4 batches x 32 k
    __shared__ __align__(16) float act_s[3072];    // 4 batches x 768
    __shared__ __align__(16) float red_s[2048];    // 16 ksub x 4 b x 32 col
    const int tid = threadIdx.x;
    const int q  = blockIdx.x >> 5;
    const int s  = (blockIdx.x >> 3) & 3;
    const int bg = blockIdx.x & 7;
    const int b0 = bg * 4;

    // stage
    if (t < TT && tid < 128) {
        const int bb = tid >> 5, kk = tid & 31;
        h1_s[bb*32 + kk] = ws[OFF_H + ((t+1)&1)*(TB*TH) + (b0+bb)*TH + q*128 + s*32 + kk];
    }
    if (t > 0) {
        for (int i = tid; i < 768; i += 512) {
            const int bb = i / 192;
            const int k0 = (i - bb*192) * 4;
            const float* src = (k0 < 512) ? &ws[OFF_H + (t&1)*(TB*TH) + (b0+bb)*TH + k0]
                                          : &ws[OFF_RVEC + (b0+bb)*256 + (k0 - 512)];
            *(float4*)&act_s[bb*768 + k0] = *(const float4*)src;
        }
    }
    __syncthreads();

    // job1: z partials, k range [q*128+s*32, +32)
    if (t < TT && tid < IFACE) {
        const int col = tid;
        float a0=0, a1=0, a2=0, a3=0;
        const float* wb = W_if + (size_t)(q*128 + s*32) * IFACE + col;
        #pragma unroll 8
        for (int kk = 0; kk < 32; ++kk) {
            const float w = *wb; wb += IFACE;
            a0 += h1_s[kk]      * w;
            a1 += h1_s[32+kk]   * w;
            a2 += h1_s[64+kk]   * w;
            a3 += h1_s[96+kk]   * w;
        }
        const size_t base = OFF_ZP + ((size_t)(q*4+s)*32 + b0) * 480 + col;
        ws[base]         = a0;
        ws[base + 480]   = a1;
        ws[base + 960]   = a2;
        ws[base + 1440]  = a3;
    }

    // job2: out(t-1) cols [q*128+s*32, +32), 4 batches, full K=768
    if (t > 0) {
        const int c0 = q*128 + s*32;
        const int col = tid & 31;
        const int ksb = tid >> 5;     // 0..15, 48 k each
        float a0=0, a1=0, a2=0, a3=0;
        for (int kk = ksb*48; kk < ksb*48 + 48; ++kk) {
            const float w = (kk < 512) ? W_pre[(size_t)kk * 512 + c0 + col]
                                       : W_rout[(size_t)(kk - 512) * 512 + c0 + col];
            a0 += act_s[kk]        * w;
            a1 += act_s[768 + kk]  * w;
            a2 += act_s[1536 + kk] * w;
            a3 += act_s[2304 + kk] * w;
        }
        red_s[(ksb*4 + 0)*32 + col] = a0;
        red_s[(ksb*4 + 1)*32 + col] = a1;
        red_s[(ksb*4 + 2)*32 + col] = a2;
        red_s[(ksb*4 + 3)*32 + col] = a3;
        __syncthreads();
        if (tid < 128) {
            const int cc = tid & 31, bb = tid >> 5;
            float ssum = 0.0f;
            #pragma unroll
            for (int ks2 = 0; ks2 < 16; ++ks2) ssum += red_s[(ks2*4 + bb)*32 + cc];
            ssum += b_pre[c0 + cc];
            out[(size_t)(t - 1) * (TB * TD) + (b0+bb) * TD + c0 + cc] = ssum;
        }
    }
}

// ---------------- kernel 3: per-batch front half (parse..ww/prec) ----------------
__global__ __launch_bounds__(512) void k_stepA(
    const float* __restrict__ b_if, float* __restrict__ ws, int t)
{
    __shared__ __align__(16) float z_s[480];
    __shared__ __align__(16) float rwf_s[1024];
    __shared__ __align__(16) float ww_old_s[256];
    __shared__ __align__(16) float ww_s[256];
    __shared__ __align__(16) float u_s[256];
    __shared__ __align__(16) float prec_s[256];
    __shared__ __align__(16) float mnorm_s[256];
    __shared__ __align__(16) float alloc_s[256];
    __shared__ __align__(16) float cw_s[256];
    __shared__ __align__(16) float keys_s[4][64];
    __shared__ __align__(16) float wkey_s[64];
    __shared__ __align__(16) float erase_s[64];
    __shared__ __align__(16) float wvec_s[64];
    __shared__ __align__(16) float rstr_s[4];
    __shared__ __align__(16) float free_s[4];
    __shared__ __align__(16) float modes_s[4][3];
    __shared__ __align__(16) float knorm_s[8];
    __shared__ __align__(16) float sredA_s[8];
    __shared__ __align__(16) float sc_s[8];   // 0 wstr 1 ag 2 wg 3 sumww 4 max 5 sum
    __shared__ __align__(16) float Pt_s[512];

    const int b   = blockIdx.x;
    const int tid = threadIdx.x;
    const float* wsM = ws + OFF_M + b * (TN * TWM);
    const float* precOld = ws + OFF_PRECA + (t & 1) * (TB * TN) + b * 256;
    float* precNew = ws + OFF_PRECA + ((t + 1) & 1) * (TB * TN) + b * 256;

    // ---- stage + z reduce ----
    if (tid < 256)       { *(float4*)&rwf_s[tid*4] = *(const float4*)&ws[OFF_RW + b*1024 + tid*4]; }
    else if (tid < 320)  { const int i = tid-256; *(float4*)&ww_old_s[i*4] = *(const float4*)&ws[OFF_WW + b*256 + i*4]; }
    else if (tid < 384)  { const int i = tid-320; *(float4*)&u_s[i*4]      = *(const float4*)&ws[OFF_USAGE + b*256 + i*4]; }
    else if (tid < 448)  { const int i = tid-384; *(float4*)&prec_s[i*4]   = *(const float4*)&precOld[i*4]; }
    else                 { const int i = tid-448; *(float4*)&mnorm_s[i*4]  = *(const float4*)&ws[OFF_MNORM + b*256 + i*4]; }
    if (tid < IFACE) {
        float zv = b_if[tid];
        #pragma unroll
        for (int p = 0; p < 16; ++p)
            zv += ws[OFF_ZP + ((size_t)p*32 + b) * 480 + tid];
        z_s[tid] = zv;
    }
    __syncthreads();

    // ---- parse ----
    if (tid < IFACE) {
        const float v = z_s[tid];
        if (tid < 256)       keys_s[tid >> 6][tid & 63] = v;
        else if (tid < 260)  rstr_s[tid - 256] = 1.0f + softpl(v);
        else if (tid < 324)  wkey_s[tid - 260] = v;
        else if (tid == 324) sc_s[0] = 1.0f + softpl(v);
        else if (tid < 389)  erase_s[tid - 325] = sigm(v);
        else if (tid < 453)  wvec_s[tid - 389] = v;
        else if (tid < 457)  free_s[tid - 453] = sigm(v);
        else if (tid == 457) sc_s[1] = sigm(v);
        else if (tid == 458) sc_s[2] = sigm(v);
    }
    __syncthreads();
    // ---- key norms + modes ----
    if (tid < 320) {
        const int w5 = tid >> 6, lane = tid & 63;
        const float v = (w5 == 0) ? wkey_s[lane] : keys_s[w5 - 1][lane];
        float s = v * v;
        #pragma unroll
        for (int m = 1; m <= 32; m <<= 1) s += __shfl_xor(s, m);
        if (lane == 0) knorm_s[w5] = fmaxf(sqrtf(s), EPSI);
    } else if (tid >= 508) {
        const int r = tid - 508;
        const float m0 = z_s[459 + r*3], m1 = z_s[460 + r*3], m2 = z_s[461 + r*3];
        const float mx = fmaxf(m0, fmaxf(m1, m2));
        const float e0 = expf(m0 - mx), e1 = expf(m1 - mx), e2 = expf(m2 - mx);
        const float s = e0 + e1 + e2;
        modes_s[r][0] = e0 / s; modes_s[r][1] = e1 / s; modes_s[r][2] = e2 / s;
    }
    __syncthreads();

    // ---- PARSE writeout + usage update ----
    if (tid < 404) {
        float v;
        if (tid < 256)       v = ((float*)keys_s)[tid];
        else if (tid < 320)  v = erase_s[tid - 256];
        else if (tid < 384)  v = wvec_s[tid - 320];
        else if (tid < 388)  v = rstr_s[tid - 384];
        else if (tid < 392)  v = knorm_s[tid - 388 + 1];
        else                 v = ((float*)modes_s)[tid - 392];
        ws[OFF_PARSE + b * 448 + tid] = v;
    }
    if (tid < 256) {
        float ret = 1.0f;
        #pragma unroll
        for (int r = 0; r < 4; ++r) ret *= 1.0f - free_s[r] * rwf_s[r*256 + tid];
        const float un = (u_s[tid] + ww_old_s[tid] - u_s[tid] * ww_old_s[tid]) * ret;
        u_s[tid] = un;
        ws[OFF_USAGE + b * 256 + tid] = un;
    }
    __syncthreads();

    // ---- allocation (stable lexicographic product) ----
    {
        const int q = tid >> 8, n = tid & 255;
        const float un = u_s[n];
        float p = 1.0f;
        #pragma unroll 8
        for (int m = q * 128; m < q * 128 + 128; ++m) {
            const float um = u_s[m];
            const bool lt = (um < un) || (um == un && m < n);
            p *= lt ? um : 1.0f;
        }
        Pt_s[q * 256 + n] = p;
    }
    __syncthreads();
    if (tid < 256)
        alloc_s[tid] = (1.0f - u_s[tid]) * Pt_s[tid] * Pt_s[256 + tid];
    __syncthreads();

    // ---- cw content sim (M_old; norms precomputed) ----
    {
        const int n = tid >> 1, q2 = tid & 1;
        const float* mp = wsM + n * 64 + q2 * 32;
        float s = 0.0f;
        #pragma unroll
        for (int it = 0; it < 8; ++it) {
            float4 mv = *(const float4*)(mp + it * 4);
            float4 kv = *(const float4*)&wkey_s[q2 * 32 + it * 4];
            s += mv.x*kv.x + mv.y*kv.y + mv.z*kv.z + mv.w*kv.w;
        }
        s += __shfl_xor(s, 1);
        if (q2 == 0) cw_s[n] = sc_s[0] * s / (knorm_s[0] * mnorm_s[n]);
    }
    __syncthreads();
    // ---- cw softmax ----
    {
        float v = 0.0f, e = 0.0f;
        if (tid < 256) {
            v = cw_s[tid];
            float m = v;
            #pragma unroll
            for (int mm = 1; mm <= 32; mm <<= 1) m = fmaxf(m, __shfl_xor(m, mm));
            if ((tid & 63) == 0) sredA_s[tid >> 6] = m;
        }
        __syncthreads();
        if (tid == 0) sc_s[4] = fmaxf(fmaxf(sredA_s[0], sredA_s[1]), fmaxf(sredA_s[2], sredA_s[3]));
        __syncthreads();
        if (tid < 256) {
            e = expf(v - sc_s[4]);
            float s2 = e;
            #pragma unroll
            for (int mm = 1; mm <= 32; mm <<= 1) s2 += __shfl_xor(s2, mm);
            if ((tid & 63) == 0) sredA_s[tid >> 6] = s2;
        }
        __syncthreads();
        if (tid == 0) sc_s[5] = sredA_s[0] + sredA_s[1] + sredA_s[2] + sredA_s[3];
        __syncthreads();
        if (tid < 256) cw_s[tid] = e / sc_s[5];
    }
    __syncthreads();

    // ---- ww, sum(ww), prec_new ----
    if (tid < 256) {
        const float wwn = sc_s[2] * (sc_s[1] * alloc_s[tid] + (1.0f - sc_s[1]) * cw_s[tid]);
        ww_s[tid] = wwn;
        ws[OFF_WW + b * 256 + tid] = wwn;
    }
    __syncthreads();
    if (tid < 256) {
        float s = ww_s[tid];
        #pragma unroll
        for (int mm = 1; mm <= 32; mm <<= 1) s += __shfl_xor(s, mm);
        if ((tid & 63) == 0) sredA_s[tid >> 6] = s;
    }
    __syncthreads();
    if (tid == 0) sc_s[3] = sredA_s[0] + sredA_s[1] + sredA_s[2] + sredA_s[3];
    __syncthreads();
    if (tid < 256)
        precNew[tid] = (1.0f - sc_s[3]) * prec_s[tid] + ww_s[tid];
}

// ---------------- kernel 4: wide link/M kernel ----------------
// grid 256 = b*8 + c (chunk c = rows [32c,32c+32)), 512 threads.
__global__ __launch_bounds__(512) void k_link(float* __restrict__ ws, int t)
{
    __shared__ __align__(16) float ww_s[256];
    __shared__ __align__(16) float prec_s[256];
    __shared__ __align__(16) float rw_s[1024];
    __shared__ __align__(16) float pk_s[448];
    __shared__ __align__(16) float Lt[32 * 257];

    const int bi = blockIdx.x;
    const int b  = bi >> 3;
    const int c  = bi & 7;
    const int tid = threadIdx.x;
    const float* precOld = ws + OFF_PRECA + (t & 1) * (TB * TN) + b * 256;

    if (tid < 64)        { *(float4*)&ww_s[tid*4] = *(const float4*)&ws[OFF_WW + b*256 + tid*4]; }
    else if (tid < 128)  { const int i = tid-64;  *(float4*)&prec_s[i*4] = *(const float4*)&precOld[i*4]; }
    else if (tid < 384)  { const int i = tid-128; *(float4*)&rw_s[i*4]   = *(const float4*)&ws[OFF_RW + b*1024 + i*4]; }
    else if (tid < 496)  { const int i = tid-384; *(float4*)&pk_s[i*4]   = *(const float4*)&ws[OFF_PARSE + b*448 + i*4]; }
    __syncthreads();

    // ---- M update + norms + cr logits for rows [32c, 32c+32) ----
    {
        const int ric = tid >> 4, c4 = (tid & 15) * 4;
        const int gi  = c * 32 + ric;
        float* mp = ws + OFF_M + b * (TN*TWM) + gi * 64 + c4;
        float4 m = *(const float4*)mp;
        const float wwi = ww_s[gi];
        float4 er = *(const float4*)&pk_s[256 + c4];
        float4 wv = *(const float4*)&pk_s[320 + c4];
        m.x = m.x * (1.0f - wwi * er.x) + wwi * wv.x;
        m.y = m.y * (1.0f - wwi * er.y) + wwi * wv.y;
        m.z = m.z * (1.0f - wwi * er.z) + wwi * wv.z;
        m.w = m.w * (1.0f - wwi * er.w) + wwi * wv.w;
        *(float4*)mp = m;
        float sn = m.x*m.x + m.y*m.y + m.z*m.z + m.w*m.w;
        float d0 = m.x*pk_s[c4]     + m.y*pk_s[c4+1]     + m.z*pk_s[c4+2]     + m.w*pk_s[c4+3];
        float d1 = m.x*pk_s[64+c4]  + m.y*pk_s[64+c4+1]  + m.z*pk_s[64+c4+2]  + m.w*pk_s[64+c4+3];
        float d2 = m.x*pk_s[128+c4] + m.y*pk_s[128+c4+1] + m.z*pk_s[128+c4+2] + m.w*pk_s[128+c4+3];
        float d3 = m.x*pk_s[192+c4] + m.y*pk_s[192+c4+1] + m.z*pk_s[192+c4+2] + m.w*pk_s[192+c4+3];
        #pragma unroll
        for (int mm = 1; mm <= 8; mm <<= 1) {
            sn += __shfl_xor(sn, mm);
            d0 += __shfl_xor(d0, mm); d1 += __shfl_xor(d1, mm);
            d2 += __shfl_xor(d2, mm); d3 += __shfl_xor(d3, mm);
        }
        if ((tid & 15) == 0) {
            const float mn = fmaxf(sqrtf(sn), EPSI);
            ws[OFF_MNORM + b*256 + gi] = mn;
            const float inv = 1.0f / mn;
            ws[OFF_CRS + b*1024 + 0*256 + gi] = pk_s[384+0] * d0 * inv / pk_s[388+0];
            ws[OFF_CRS + b*1024 + 1*256 + gi] = pk_s[384+1] * d1 * inv / pk_s[388+1];
            ws[OFF_CRS + b*1024 + 2*256 + gi] = pk_s[384+2] * d2 * inv / pk_s[388+2];
            ws[OFF_CRS + b*1024 + 3*256 + gi] = pk_s[384+3] * d3 * inv / pk_s[388+3];
        }
    }

    // ---- link rows update (phase A) ----
    {
        const int j = tid & 255, p = tid >> 8;
        const float wwj = ww_s[j], pj = prec_s[j];
        #pragma unroll 4
        for (int it = 0; it < 16; ++it) {
            const int ric = it * 2 + p;
            const int gi  = c * 32 + ric;
            float* lp = ws + OFF_LINK + (size_t)b * (TN*TN) + (size_t)gi * 256 + j;
            const float wwi = ww_s[gi];
            float v = (1.0f - wwi - wwj) * (*lp) + wwi * pj;
            if (j == gi) v = 0.0f;
            *lp = v;
            Lt[ric * 257 + j] = v;
        }
    }
    __syncthreads();

    // ---- fw (phase B): fw[r][i] = sum_j L[i][j]*rw[r][j] ----
    {
        const int ric = tid >> 4, g = tid & 15;
        const int gi = c * 32 + ric;
        float f0=0, f1=0, f2=0, f3=0;
        #pragma unroll 4
        for (int jj = 0; jj < 16; ++jj) {
            const int j = g * 16 + jj;
            const float v = Lt[ric * 257 + j];
            f0 += v * rw_s[j]; f1 += v * rw_s[256+j];
            f2 += v * rw_s[512+j]; f3 += v * rw_s[768+j];
        }
        #pragma unroll
        for (int mm = 1; mm <= 8; mm <<= 1) {
            f0 += __shfl_xor(f0, mm); f1 += __shfl_xor(f1, mm);
            f2 += __shfl_xor(f2, mm); f3 += __shfl_xor(f3, mm);
        }
        if (g == 0) {
            ws[OFF_FW + b*1024 + gi]       = f0;
            ws[OFF_FW + b*1024 + 256 + gi] = f1;
            ws[OFF_FW + b*1024 + 512 + gi] = f2;
            ws[OFF_FW + b*1024 + 768 + gi] = f3;
        }
    }

    // ---- bw partials (phase C): bwp[r][j] = sum_{i in chunk} L[i][j]*rw[r][i] ----
    {
        const int j = tid & 255, p = tid >> 8;
        float b0=0, b1=0, b2=0, b3=0;
        #pragma unroll 4
        for (int it = 0; it < 16; ++it) {
            const int ric = p * 16 + it;
            const int gi  = c * 32 + ric;
            const float v = Lt[ric * 257 + j];
            b0 += v * rw_s[gi]; b1 += v * rw_s[256+gi];
            b2 += v * rw_s[512+gi]; b3 += v * rw_s[768+gi];
        }
        __syncthreads();
        if (p == 1) { Lt[j] = b0; Lt[256+j] = b1; Lt[512+j] = b2; Lt[768+j] = b3; }
        __syncthreads();
        if (p == 0) {
            ws[OFF_BWP + (size_t)bi*1024 + j]       = b0 + Lt[j];
            ws[OFF_BWP + (size_t)bi*1024 + 256 + j] = b1 + Lt[256+j];
            ws[OFF_BWP + (size_t)bi*1024 + 512 + j] = b2 + Lt[512+j];
            ws[OFF_BWP + (size_t)bi*1024 + 768 + j] = b3 + Lt[768+j];
        }
    }
}

// ---------------- kernel 5: per-batch back half (cr softmax, rw, rvec) ----------------
__global__ __launch_bounds__(512) void k_stepB(float* __restrict__ ws, int t)
{
    __shared__ __align__(16) float cr_s[4][256];
    __shared__ __align__(16) float rw2_s[1024];
    __shared__ __align__(16) float Lt2[512];
    __shared__ __align__(16) float md[12];
    __shared__ __align__(16) float sredA_s[8];
    __shared__ __align__(16) float sredB_s[8];
    __shared__ __align__(16) float gmax_s[4];
    __shared__ __align__(16) float gsum_s[4];

    const int b   = blockIdx.x;
    const int tid = threadIdx.x;
    const float* wsM = ws + OFF_M + b * (TN * TWM);

    ((float*)cr_s)[tid]       = ws[OFF_CRS + b*1024 + tid];
    ((float*)cr_s)[tid + 512] = ws[OFF_CRS + b*1024 + tid + 512];
    if (tid < 12) md[tid] = ws[OFF_PARSE + b*448 + 392 + tid];
    __syncthreads();

    // ---- cr softmax (heads rr, rr+2) ----
    {
        const int rr = tid >> 8, n = tid & 255, wv = tid >> 6, lane = tid & 63;
        float v0 = cr_s[rr][n], v1 = cr_s[rr + 2][n];
        float m0 = v0, m1 = v1;
        #pragma unroll
        for (int mm = 1; mm <= 32; mm <<= 1) {
            m0 = fmaxf(m0, __shfl_xor(m0, mm));
            m1 = fmaxf(m1, __shfl_xor(m1, mm));
        }
        if (lane == 0) { sredA_s[wv] = m0; sredB_s[wv] = m1; }
        __syncthreads();
        if (tid < 4) {
            const float* base = (tid & 2) ? sredB_s : sredA_s;
            const int off = (tid & 1) * 4;
            gmax_s[tid] = fmaxf(fmaxf(base[off], base[off+1]), fmaxf(base[off+2], base[off+3]));
        }
        __syncthreads();
        const float e0 = expf(v0 - gmax_s[rr]);
        const float e1 = expf(v1 - gmax_s[rr + 2]);
        float s0 = e0, s1 = e1;
        #pragma unroll
        for (int mm = 1; mm <= 32; mm <<= 1) {
            s0 += __shfl_xor(s0, mm); s1 += __shfl_xor(s1, mm);
        }
        if (lane == 0) { sredA_s[wv] = s0; sredB_s[wv] = s1; }
        __syncthreads();
        if (tid < 4) {
            const float* base = (tid & 2) ? sredB_s : sredA_s;
            const int off = (tid & 1) * 4;
            gsum_s[tid] = base[off] + base[off+1] + base[off+2] + base[off+3];
        }
        __syncthreads();
        cr_s[rr][n]     = e0 / gsum_s[rr];
        cr_s[rr + 2][n] = e1 / gsum_s[rr + 2];
    }
    __syncthreads();

    // ---- bw reduce + rw update ----
    {
        const int rr = tid >> 8, n = tid & 255;
        #pragma unroll
        for (int p = 0; p < 2; ++p) {
            const int r = rr + 2 * p;
            float bw = 0.0f;
            #pragma unroll
            for (int c = 0; c < 8; ++c)
                bw += ws[OFF_BWP + (size_t)(b*8 + c)*1024 + r*256 + n];
            const float fw = ws[OFF_FW + b*1024 + r*256 + n];
            const float v = md[r*3] * bw + md[r*3+1] * cr_s[r][n] + md[r*3+2] * fw;
            rw2_s[r*256 + n] = v;
            ws[OFF_RW + b*1024 + r*256 + n] = v;
        }
    }
    __syncthreads();

    // ---- rvec = rw_new @ M_new ----
    {
        const int q2 = tid >> 8, r = (tid >> 6) & 3, w = tid & 63;
        float s = 0.0f;
        #pragma unroll 4
        for (int n = q2 * 128; n < q2 * 128 + 128; ++n)
            s += rw2_s[r*256 + n] * wsM[n * 64 + w];
        Lt2[q2 * 256 + r * 64 + w] = s;
    }
    __syncthreads();
    if (tid < 256)
        ws[OFF_RVEC + b * 256 + tid] = Lt2[tid] + Lt2[256 + tid];
}

extern "C" void kernel_launch(void* const* d_in, const int* in_sizes, int n_in,
                              void* d_out, int out_size, void* d_ws, size_t ws_size,
                              hipStream_t stream) {
    const float* emb    = (const float*)d_in[0];
    const float* Wx     = (const float*)d_in[1];
    const float* Wh     = (const float*)d_in[2];
    const float* b_lstm = (const float*)d_in[3];
    const float* W_pre  = (const float*)d_in[4];
    const float* b_pre  = (const float*)d_in[5];
    const float* W_if   = (const float*)d_in[6];
    const float* b_if   = (const float*)d_in[7];
    const float* W_rout = (const float*)d_in[8];
    float* out = (float*)d_out;
    float* ws  = (float*)d_ws;

    k_init<<<(TOTAL_STATE + 255) / 256, 256, 0, stream>>>(ws);
    for (int t = 0; t < TT; ++t) {
        k_gates<<<128, 512, 0, stream>>>(emb, Wx, Wh, b_lstm, ws, t);
        k_iface<<<128, 512, 0, stream>>>(W_if, W_pre, b_pre, W_rout, ws, out, t);
        k_stepA<<<32, 512, 0, stream>>>(b_if, ws, t);
        k_link<<<256, 512, 0, stream>>>(ws, t);
        k_stepB<<<32, 512, 0, stream>>>(ws, t);
    }
    // final out(127)
    k_iface<<<128, 512, 0, stream>>>(W_if, W_pre, b_pre, W_rout, ws, out, TT);
}